// Round 9
// baseline (864.743 us; speedup 1.0000x reference)
//
#include <hip/hip_runtime.h>
#include <hip/hip_bf16.h>
#include <stdint.h>

// Problem constants (fixed by the reference)
#define N_NODES 50000
#define E_EDGES 640000
#define NB_TILES 782           // ceil(50000/64)
#define NBUCKET 6256           // 8 rels * 782 tiles
#define CAP 256                // bucket capacity; lambda=102.3, 15-sigma headroom
#define DUMMY 50000u           // payload: src=50000 (zeroed xb row), dl=0

typedef __attribute__((ext_vector_type(8))) short short8;   // 8 bf16 (MFMA A/B frag)
typedef __attribute__((ext_vector_type(4))) float float4v;  // MFMA C/D frag

__device__ __forceinline__ unsigned short f32_to_bf16(float f) {
  uint32_t u = __float_as_uint(f);
  u += 0x7fffu + ((u >> 16) & 1u);          // round-to-nearest-even
  return (unsigned short)(u >> 16);
}

// ---------------------------------------------------------------------------
// K_pre: fused  (a) x -> bf16 xb                  [blocks 0..6249]
//               (b) weight transpose+cvt -> wTg   [blocks 6250..6260]
//               (c) DIRECT bucket fill: bkt = ety*782 + (dst>>6);
//                   slot = atomicAdd(cnt); payload = src | (dst&63)<<20
// ---------------------------------------------------------------------------
__global__ __launch_bounds__(256) void k_pre(
    const float* __restrict__ x, const float* __restrict__ W_rel,
    const float* __restrict__ w1W, const float* __restrict__ m1W,
    const float* __restrict__ m2W, const int* __restrict__ src,
    const int* __restrict__ dst, const int* __restrict__ ety,
    unsigned short* __restrict__ xb, unsigned short* __restrict__ wTg,
    int* __restrict__ cnt, uint32_t* __restrict__ eidx) {
  int b = blockIdx.x;
  if (b < 6250) {
    int idx = b * 256 + threadIdx.x;                 // 1.6M float4 groups
    float4 v = ((const float4*)x)[idx];
    uint32_t p0 = (uint32_t)f32_to_bf16(v.x) | ((uint32_t)f32_to_bf16(v.y) << 16);
    uint32_t p1 = (uint32_t)f32_to_bf16(v.z) | ((uint32_t)f32_to_bf16(v.w) << 16);
    ((uint2*)xb)[idx] = make_uint2(p0, p1);
  } else if (b < 6261) {
    int m = b - 6250;                                // 0..7 W_rel, 8 w1, 9 m1, 10 m2
    const float* srcp = (m < 8) ? (W_rel + (size_t)m * 16384)
                                : (m == 8 ? w1W : (m == 9 ? m1W : m2W));
    unsigned short* dstp = wTg + (size_t)m * 16384;
    for (int i = 0; i < 64; ++i) {
      int idx = threadIdx.x + i * 256;               // o*128 + k
      int o = idx >> 7, k = idx & 127;
      dstp[idx] = f32_to_bf16(srcp[k * 128 + o]);
    }
  } else {
    int e = (b - 6261) * 256 + threadIdx.x;          // 2500*256 == E exactly
    int d = dst[e];
    int bkt = ety[e] * NB_TILES + (d >> 6);
    int p = atomicAdd(&cnt[bkt], 1);
    if (p < CAP)
      eidx[((uint32_t)bkt << 8) + p] = (uint32_t)src[e] | ((uint32_t)(d & 63) << 20);
  }
}

// ---------------------------------------------------------------------------
// gemm_tile_g: one wave computes a 16x128 tile; A from LDS (wave-private
// rows), B read DIRECTLY from global wTg (L2-resident).
// D layout: col=lane&15, row=(lane>>4)*4+i.
// ---------------------------------------------------------------------------
__device__ __forceinline__ void gemm_tile_g(const short (*A)[136],
    const unsigned short* __restrict__ Bt, int wave, int lane, float4v acc[8]) {
  int arow = wave * 16 + (lane & 15);
  int koff = (lane >> 4) * 8;
  #pragma unroll
  for (int kk = 0; kk < 4; ++kk) {
    short8 a = *(const short8*)&A[arow][kk * 32 + koff];
    #pragma unroll
    for (int n = 0; n < 8; ++n) {
      short8 b = *(const short8*)&Bt[(size_t)(n * 16 + (lane & 15)) * 128 + kk * 32 + koff];
      acc[n] = __builtin_amdgcn_mfma_f32_16x16x32_bf16(a, b, acc[n], 0, 0, 0);
    }
  }
}

// 8-slot macros: named scalars only (rule #20), zero branches in hot loop.
#define SLOT_PRO(d) \
  p##d = es[wave + 4 * d]; \
  w##d = xb32[(size_t)(p##d & 0xFFFFFu) * 64 + lane];
#define SLOT_LOAD(d) \
  uint32_t q##d = es[gb + 4 * d]; \
  uint32_t v##d = xb32[(size_t)(q##d & 0xFFFFFu) * 64 + lane];
#define SLOT_CONSUME(d) { \
  int dl = (int)(p##d >> 20); \
  atomicAdd(&ftd[dl][lane],      __uint_as_float(w##d << 16)); \
  atomicAdd(&ftd[dl][64 + lane], __uint_as_float(w##d & 0xffff0000u)); \
  p##d = q##d; w##d = v##d; }

// ---------------------------------------------------------------------------
// K_fused: per 64-dst-node tile.
//   rel loop r=0..7:
//     stage bucket edge list -> LDS es[288], DUMMY-padded to mult of 32
//     branch-free 8-slot pipelined gather (8 outstanding 256B loads/wave),
//       LDS ds_add scatter into deinterleaved ftd (2 lanes/bank = free)
//     convert ftd->bf16 xs (re-zero in same pass), MFMA vs W_r, accumulate
//   then acc += x@w1 ; h1=acc+b1 ; h2=relu(h1@m1+m1b) ; out=h2@m2+m2b.
// ---------------------------------------------------------------------------
__global__ __launch_bounds__(256, 3) void k_fused(
    const unsigned short* __restrict__ xb, const unsigned short* __restrict__ wTg,
    const int* __restrict__ cnt, const uint32_t* __restrict__ eidx,
    const float* __restrict__ w1b, const float* __restrict__ m1b,
    const float* __restrict__ m2b, float* __restrict__ out) {
  __shared__ float ftd[64][128];         // 32 KB; [row][lane]=col 2l, [row][64+l]=col 2l+1
  __shared__ short xs[64][136];          // 17.4 KB bf16 MFMA A staging
  __shared__ uint32_t es[288];           // 1.15 KB edge list (+1 dummy group)
  int tid = threadIdx.x, wave = tid >> 6, lane = tid & 63;
  int tile0 = blockIdx.x * 64;
  const uint32_t* xb32 = (const uint32_t*)xb;

  float4v acc[8];
  #pragma unroll
  for (int n = 0; n < 8; ++n) acc[n] = (float4v){0.f, 0.f, 0.f, 0.f};

  // zero own rows of ftd (wave-private rows)
  #pragma unroll
  for (int i = 0; i < 16; ++i) {
    ftd[wave * 16 + i][lane] = 0.f;
    ftd[wave * 16 + i][64 + lane] = 0.f;
  }

  // ---- relation loop -------------------------------------------------
  for (int r = 0; r < 8; ++r) {
    __syncthreads();                     // ftd zeros visible; es reusable

    int bkt = r * NB_TILES + blockIdx.x;
    int n = cnt[bkt]; if (n > CAP) n = CAP;
    int npad = (n + 31) & ~31;           // dummy-padded count (LDS only)
    {
      uint32_t v = DUMMY;
      if (tid < n) v = eidx[((uint32_t)bkt << 8) + tid];
      es[tid] = v;
      if (tid < 32) es[256 + tid] = DUMMY;
    }
    __syncthreads();                     // es visible

    // branch-free 8-slot rolling pipeline over groups of 32 edges
    uint32_t p0, p1, p2, p3, p4, p5, p6, p7;
    uint32_t w0, w1, w2, w3, w4, w5, w6, w7;
    SLOT_PRO(0) SLOT_PRO(1) SLOT_PRO(2) SLOT_PRO(3)
    SLOT_PRO(4) SLOT_PRO(5) SLOT_PRO(6) SLOT_PRO(7)
    for (int g = 1; g <= (npad >> 5); ++g) {
      int gb = g * 32 + wave;            // next group base (dummy group at end)
      SLOT_LOAD(0) SLOT_LOAD(1) SLOT_LOAD(2) SLOT_LOAD(3)
      SLOT_LOAD(4) SLOT_LOAD(5) SLOT_LOAD(6) SLOT_LOAD(7)
      SLOT_CONSUME(0) SLOT_CONSUME(1) SLOT_CONSUME(2) SLOT_CONSUME(3)
      SLOT_CONSUME(4) SLOT_CONSUME(5) SLOT_CONSUME(6) SLOT_CONSUME(7)
    }
    __syncthreads();                     // all scatter-adds done

    // convert own 16 rows -> bf16 xs, re-zero ftd for next r (same pass)
    #pragma unroll
    for (int i = 0; i < 16; ++i) {
      int row = wave * 16 + i;
      float lo = ftd[row][lane], hi = ftd[row][64 + lane];
      ftd[row][lane] = 0.f; ftd[row][64 + lane] = 0.f;
      uint32_t pk = (uint32_t)f32_to_bf16(lo) | ((uint32_t)f32_to_bf16(hi) << 16);
      *(uint32_t*)&xs[row][lane * 2] = pk;
    }
    gemm_tile_g(xs, wTg + (size_t)r * 16384, wave, lane, acc);
  }

  // ---- acc += x_tile @ w1 (xs rows wave-private; no barrier needed) ---
  #pragma unroll
  for (int i = 0; i < 16; ++i) {
    int row = wave * 16 + i;
    int node = tile0 + row;
    uint32_t pv = (node < N_NODES) ? xb32[(size_t)node * 64 + lane] : 0u;
    *(uint32_t*)&xs[row][lane * 2] = pv;
  }
  gemm_tile_g(xs, wTg + (size_t)8 * 16384, wave, lane, acc);

  // h1 = acc + w1b  -> xs (bf16)   [agg already accumulated in acc]
  #pragma unroll
  for (int n = 0; n < 8; ++n)
    #pragma unroll
    for (int i = 0; i < 4; ++i) {
      int row = wave * 16 + (lane >> 4) * 4 + i;
      int col = n * 16 + (lane & 15);
      xs[row][col] = (short)f32_to_bf16(acc[n][i] + w1b[col]);
    }

  // ---- h2 = relu(h1 @ m1 + m1b) --------------------------------------
  #pragma unroll
  for (int n = 0; n < 8; ++n) acc[n] = (float4v){0.f, 0.f, 0.f, 0.f};
  gemm_tile_g(xs, wTg + (size_t)9 * 16384, wave, lane, acc);
  #pragma unroll
  for (int n = 0; n < 8; ++n)
    #pragma unroll
    for (int i = 0; i < 4; ++i) {
      int row = wave * 16 + (lane >> 4) * 4 + i;
      int col = n * 16 + (lane & 15);
      float v = acc[n][i] + m1b[col];
      xs[row][col] = (short)f32_to_bf16(v > 0.f ? v : 0.f);
    }

  // ---- out = h2 @ m2 + m2b -------------------------------------------
  #pragma unroll
  for (int n = 0; n < 8; ++n) acc[n] = (float4v){0.f, 0.f, 0.f, 0.f};
  gemm_tile_g(xs, wTg + (size_t)10 * 16384, wave, lane, acc);
  #pragma unroll
  for (int n = 0; n < 8; ++n)
    #pragma unroll
    for (int i = 0; i < 4; ++i) {
      int row = wave * 16 + (lane >> 4) * 4 + i;
      int col = n * 16 + (lane & 15);
      int node = tile0 + row;
      if (node < N_NODES) out[(size_t)node * 128 + col] = acc[n][i] + m2b[col];
    }
}

// ---------------------------------------------------------------------------
extern "C" void kernel_launch(void* const* d_in, const int* in_sizes, int n_in,
                              void* d_out, int out_size, void* d_ws, size_t ws_size,
                              hipStream_t stream) {
  const float* x     = (const float*)d_in[0];
  const int*   src   = (const int*)d_in[1];
  const int*   dst   = (const int*)d_in[2];
  const int*   ety   = (const int*)d_in[3];
  const float* W_rel = (const float*)d_in[4];
  const float* w1W   = (const float*)d_in[5];
  const float* w1b   = (const float*)d_in[6];
  const float* m1W   = (const float*)d_in[7];
  const float* m1b   = (const float*)d_in[8];
  const float* m2W   = (const float*)d_in[9];
  const float* m2b   = (const float*)d_in[10];
  float* out = (float*)d_out;

  // Workspace layout (bytes):
  char* ws = (char*)d_ws;
  unsigned short* wTg  = (unsigned short*)ws;               // 360,448 (pad 512K)
  unsigned short* xb   = (unsigned short*)(ws + 524288);    // 50001 rows = 12,800,256
  int*            cnt  = (int*)(ws + 13324800);             // 25,024 (pad 32K)
  uint32_t*       eidx = (uint32_t*)(ws + 13357568);        // NBUCKET*CAP*4 = 6,406,144

  hipMemsetAsync(cnt, 0, (size_t)NBUCKET * 4, stream);
  hipMemsetAsync((char*)xb + (size_t)N_NODES * 256, 0, 256, stream);  // dummy row
  k_pre<<<8761, 256, 0, stream>>>(x, W_rel, w1W, m1W, m2W, src, dst, ety,
                                  xb, wTg, cnt, eidx);
  k_fused<<<NB_TILES, 256, 0, stream>>>(xb, wTg, cnt, eidx, w1b, m1b, m2b, out);
}